// Round 2
// baseline (74.808 us; speedup 1.0000x reference)
//
#include <hip/hip_runtime.h>
#include <math.h>

#define NB   32
#define SEQ  2048
#define HD   1024
#define CDIM 256
#define VOC  64

__device__ __forceinline__ float dot4(float4 a, float4 b) {
    return a.x*b.x + a.y*b.y + a.z*b.z + a.w*b.w;
}

// ---------------- attention flash body (softmax is h_new-independent: constant shift)
// one block = one (b, 64-row chunk); 4 waves, rows interleaved across waves in groups of 4
__device__ void attn_body(int bid, const float* __restrict__ enc, const int* __restrict__ lens,
                          const float* __restrict__ attn_w, float* __restrict__ part)
{
    int b = bid >> 5, chunk = bid & 31;
    int t = threadIdx.x, w = t >> 6, lane = t & 63;
    int len = lens[b];
    int sbase = chunk * 64;

    float4 we[4], ctx[4];
    #pragma unroll
    for (int i = 0; i < 4; ++i) {
        we[i]  = *(const float4*)(attn_w + i * 256 + lane * 4);
        ctx[i] = make_float4(0.f, 0.f, 0.f, 0.f);
    }
    float m = -1e30f, l = 0.f;
    const float* ebase = enc + (size_t)b * SEQ * HD + lane * 4;

    for (int g = 0; g < 4; ++g) {
        int s0 = sbase + g * 16 + w * 4;           // this wave's group of 4 rows
        if (s0 >= len) break;                      // wave-uniform
        float4 e[4][4];
        #pragma unroll
        for (int r = 0; r < 4; ++r) {
            const float* ep = ebase + (size_t)(s0 + r) * HD;
            #pragma unroll
            for (int i = 0; i < 4; ++i) e[r][i] = *(const float4*)(ep + i * 256);
        }
        float v[4];
        #pragma unroll
        for (int r = 0; r < 4; ++r)
            v[r] = dot4(e[r][0], we[0]) + dot4(e[r][1], we[1])
                 + dot4(e[r][2], we[2]) + dot4(e[r][3], we[3]);
        #pragma unroll
        for (int off = 32; off > 0; off >>= 1) {
            #pragma unroll
            for (int r = 0; r < 4; ++r) v[r] += __shfl_xor(v[r], off, 64);
        }
        #pragma unroll
        for (int r = 0; r < 4; ++r) if (s0 + r >= len) v[r] = -1e30f;
        float vmax = fmaxf(fmaxf(v[0], v[1]), fmaxf(v[2], v[3]));
        if (vmax > m) {                            // batched rescale, wave-uniform
            float beta = __expf(m - vmax);
            l *= beta;
            #pragma unroll
            for (int i = 0; i < 4; ++i) {
                ctx[i].x *= beta; ctx[i].y *= beta; ctx[i].z *= beta; ctx[i].w *= beta;
            }
            m = vmax;
        }
        float p[4];
        #pragma unroll
        for (int r = 0; r < 4; ++r) p[r] = __expf(v[r] - m);
        l += p[0] + p[1] + p[2] + p[3];
        #pragma unroll
        for (int i = 0; i < 4; ++i) {
            ctx[i].x += p[0]*e[0][i].x + p[1]*e[1][i].x + p[2]*e[2][i].x + p[3]*e[3][i].x;
            ctx[i].y += p[0]*e[0][i].y + p[1]*e[1][i].y + p[2]*e[2][i].y + p[3]*e[3][i].y;
            ctx[i].z += p[0]*e[0][i].z + p[1]*e[1][i].z + p[2]*e[2][i].z + p[3]*e[3][i].z;
            ctx[i].w += p[0]*e[0][i].w + p[1]*e[1][i].w + p[2]*e[2][i].w + p[3]*e[3][i].w;
        }
    }
    // combine the block's 4 waves
    __shared__ float ctxs[4][1024];
    __shared__ float wm[4], wl[4];
    #pragma unroll
    for (int i = 0; i < 4; ++i)
        *(float4*)&ctxs[w][i * 256 + lane * 4] = ctx[i];
    if (lane == 0) { wm[w] = m; wl[w] = l; }
    __syncthreads();
    float mb = fmaxf(fmaxf(wm[0], wm[1]), fmaxf(wm[2], wm[3]));
    float f0 = __expf(wm[0] - mb), f1 = __expf(wm[1] - mb);
    float f2 = __expf(wm[2] - mb), f3 = __expf(wm[3] - mb);
    float lb = f0 * wl[0] + f1 * wl[1] + f2 * wl[2] + f3 * wl[3];
    float* rec = part + (size_t)bid * 1032;
    #pragma unroll
    for (int i = 0; i < 4; ++i) {
        int hh = t + i * 256;
        rec[hh] = f0 * ctxs[0][hh] + f1 * ctxs[1][hh] + f2 * ctxs[2][hh] + f3 * ctxs[3][hh];
    }
    if (t == 0) { rec[1024] = mb; rec[1025] = lb; }
}

// ---------------- split-K GEMM body (LSTM: X=[emb|h_prev] K=1280, W=[w_ih|w_hh] N=4096)
__device__ void gemm0_body(int gid, const float* __restrict__ emb, const int* __restrict__ chars,
                           const float* __restrict__ h_prev,
                           const float* __restrict__ w_ih, const float* __restrict__ w_hh,
                           float* __restrict__ zpart)
{
    const int n0    = (gid & 255) * 16;
    const int ky    = gid >> 8;
    const int kbase = ky * 320;

    __shared__ float Xs[32][33];
    __shared__ float Ws[32][17];

    const int t  = threadIdx.x;
    const int nn = t & 15, bb = t >> 4;
    float acc0 = 0.f, acc1 = 0.f;

    for (int k0 = kbase; k0 < kbase + 320; k0 += 32) {
        {   // X tile
            int b = t >> 3, kk = (t & 7) * 4;
            int k = k0 + kk;
            float4 xv;
            if (k < CDIM) xv = *(const float4*)(emb + chars[b] * CDIM + k);
            else          xv = *(const float4*)(h_prev + b * HD + (k - CDIM));
            Xs[kk + 0][b] = xv.x; Xs[kk + 1][b] = xv.y;
            Xs[kk + 2][b] = xv.z; Xs[kk + 3][b] = xv.w;
        }
        {   // W tile
            int nl = t >> 4, kk = (t & 15) * 2;
            int n = n0 + nl, k = k0 + kk;
            float2 wv;
            if (k < CDIM) wv = *(const float2*)(w_ih + n * CDIM + k);
            else          wv = *(const float2*)(w_hh + n * HD + (k - CDIM));
            Ws[kk + 0][nl] = wv.x; Ws[kk + 1][nl] = wv.y;
        }
        __syncthreads();
        #pragma unroll
        for (int k = 0; k < 32; ++k) {
            float wv = Ws[k][nn];
            acc0 += wv * Xs[k][bb];
            acc1 += wv * Xs[k][bb + 16];
        }
        __syncthreads();
    }
    zpart[(size_t)(ky * 32 + bb     ) * 4096 + n0 + nn] = acc0;
    zpart[(size_t)(ky * 32 + bb + 16) * 4096 + n0 + nn] = acc1;
}

// ---------------- K1: attention (blocks 0..1023) ∪ LSTM gemm (blocks 1024..2047)
__global__ void __launch_bounds__(256) attn_gemm0(
    const float* __restrict__ enc, const int* __restrict__ lens,
    const float* __restrict__ attn_w, float* __restrict__ part,
    const float* __restrict__ emb, const int* __restrict__ chars,
    const float* __restrict__ h_prev,
    const float* __restrict__ w_ih, const float* __restrict__ w_hh,
    float* __restrict__ zpart)
{
    if (blockIdx.x < 1024) attn_body(blockIdx.x, enc, lens, attn_w, part);
    else                   gemm0_body(blockIdx.x - 1024, emb, chars, h_prev, w_ih, w_hh, zpart);
}

// ---------------- K2: LSTM gate epilogue (blocks 0..127) ∪ attention combine (128..255)
__global__ void gates_combine(const float* __restrict__ zpart,
                              const float* __restrict__ b_ih, const float* __restrict__ b_hh,
                              const float* __restrict__ c_prev, const float* __restrict__ part,
                              float* __restrict__ d_out, float* __restrict__ xcat2)
{
    int t = threadIdx.x;
    if (blockIdx.x < 128) {
        int idx = blockIdx.x * 256 + t;           // 32*1024
        int b = idx >> 10, j = idx & 1023;
        float z[4];
        #pragma unroll
        for (int g = 0; g < 4; ++g) {
            int n = g * 1024 + j;
            float v = b_ih[n] + b_hh[n];
            #pragma unroll
            for (int s = 0; s < 4; ++s) v += zpart[(size_t)(s * 32 + b) * 4096 + n];
            z[g] = v;
        }
        float gi = 1.f / (1.f + expf(-z[0]));
        float gf = 1.f / (1.f + expf(-z[1]));
        float gg = tanhf(z[2]);
        float go = 1.f / (1.f + expf(-z[3]));
        float c = gf * c_prev[idx] + gi * gg;
        float h = go * tanhf(c);
        d_out[2048 + idx]         = h;            // h_new
        d_out[2048 + 32768 + idx] = c;            // c_new
        xcat2[b * 2048 + 1024 + j] = h;
    } else {
        int bid = blockIdx.x - 128;
        int b = bid >> 2, slice = bid & 3;
        __shared__ float sm[32], sl[32];
        if (t < 32) {
            const float* rec = part + (size_t)(b * 32 + t) * 1032;
            sm[t] = rec[1024]; sl[t] = rec[1025];
        }
        __syncthreads();
        float mg = -1e30f;
        #pragma unroll
        for (int i = 0; i < 32; ++i) mg = fmaxf(mg, sm[i]);
        float L = 0.f;
        #pragma unroll
        for (int i = 0; i < 32; ++i) L += __expf(sm[i] - mg) * sl[i];
        int hh = slice * 256 + t;
        float acc = 0.f;
        for (int i = 0; i < 32; ++i)
            acc += __expf(sm[i] - mg) * part[(size_t)(b * 32 + i) * 1032 + hh];
        xcat2[b * 2048 + hh] = acc / L;
    }
}

// ---------------- K3: concat projection split-K (X=xcat2 K=2048, W=concat_w N=1024, KSPLIT=8)
__global__ void __launch_bounds__(256) gemm_concat(
    const float* __restrict__ xcat2, const float* __restrict__ concat_w,
    float* __restrict__ nhpart)
{
    const int n0    = blockIdx.x * 16;
    const int kbase = blockIdx.y * 256;

    __shared__ float Xs[32][33];
    __shared__ float Ws[32][17];

    const int t  = threadIdx.x;
    const int nn = t & 15, bb = t >> 4;
    float acc0 = 0.f, acc1 = 0.f;

    for (int k0 = kbase; k0 < kbase + 256; k0 += 32) {
        {
            int b = t >> 3, kk = (t & 7) * 4;
            float4 xv = *(const float4*)(xcat2 + b * 2048 + k0 + kk);
            Xs[kk + 0][b] = xv.x; Xs[kk + 1][b] = xv.y;
            Xs[kk + 2][b] = xv.z; Xs[kk + 3][b] = xv.w;
        }
        {
            int nl = t >> 4, kk = (t & 15) * 2;
            float2 wv = *(const float2*)(concat_w + (n0 + nl) * 2048 + k0 + kk);
            Ws[kk + 0][nl] = wv.x; Ws[kk + 1][nl] = wv.y;
        }
        __syncthreads();
        #pragma unroll
        for (int k = 0; k < 32; ++k) {
            float wv = Ws[k][nn];
            acc0 += wv * Xs[k][bb];
            acc1 += wv * Xs[k][bb + 16];
        }
        __syncthreads();
    }
    nhpart[(size_t)(blockIdx.y * 32 + bb     ) * 1024 + n0 + nn] = acc0;
    nhpart[(size_t)(blockIdx.y * 32 + bb + 16) * 1024 + n0 + nn] = acc1;
}

// ---------------- K4: nh = tanh(Σ partials + b), then vocab projection — one block per b
__global__ void nh_out(const float* __restrict__ nhpart, const float* __restrict__ concat_b,
                       const float* __restrict__ out_w, const float* __restrict__ out_b,
                       float* __restrict__ d_out)
{
    int b = blockIdx.x, t = threadIdx.x;
    __shared__ float nh[1024];
    #pragma unroll
    for (int j = 0; j < 4; ++j) {
        int n = t + j * 256;
        float v = concat_b[n];
        #pragma unroll
        for (int s = 0; s < 8; ++s) v += nhpart[(size_t)(s * 32 + b) * 1024 + n];
        nh[n] = tanhf(v);
    }
    __syncthreads();
    int w = t >> 6, lane = t & 63;
    const float* nr = nh + lane * 4;
    #pragma unroll
    for (int vv = 0; vv < 16; ++vv) {
        int v = w * 16 + vv;
        const float* wr = out_w + v * 1024 + lane * 4;
        float acc = 0.f;
        #pragma unroll
        for (int i = 0; i < 4; ++i) {
            float4 wv = *(const float4*)(wr + i * 256);
            float4 nv = *(const float4*)(nr + i * 256);
            acc += dot4(wv, nv);
        }
        #pragma unroll
        for (int off = 32; off > 0; off >>= 1) acc += __shfl_xor(acc, off, 64);
        if (lane == 0) d_out[b * 64 + v] = acc + out_b[v];
    }
}

extern "C" void kernel_launch(void* const* d_in, const int* in_sizes, int n_in,
                              void* d_out, int out_size, void* d_ws, size_t ws_size,
                              hipStream_t stream)
{
    const int*   chars    = (const int*)  d_in[0];
    const float* h_prev   = (const float*)d_in[1];
    const float* c_prev   = (const float*)d_in[2];
    const int*   lens     = (const int*)  d_in[3];
    const float* enc      = (const float*)d_in[4];
    const float* emb      = (const float*)d_in[5];
    const float* w_ih     = (const float*)d_in[6];
    const float* w_hh     = (const float*)d_in[7];
    const float* b_ih     = (const float*)d_in[8];
    const float* b_hh     = (const float*)d_in[9];
    const float* attn_w   = (const float*)d_in[10];
    const float* concat_w = (const float*)d_in[12];
    const float* concat_b = (const float*)d_in[13];
    const float* out_w    = (const float*)d_in[14];
    const float* out_b    = (const float*)d_in[15];
    float* out = (float*)d_out;

    float* ws = (float*)d_ws;
    float* zpart  = ws;                      // 4*32*4096   = 524288
    float* xcat2  = zpart + 524288;          // 32*2048     = 65536
    float* part   = xcat2 + 65536;           // 1024*1032   = 1056768
    float* nhpart = part + 1056768;          // 8*32*1024   = 262144

    // K1: attention partials (blocks 0..1023) ∪ LSTM split-K gemm (blocks 1024..2047)
    attn_gemm0<<<dim3(2048), 256, 0, stream>>>(enc, lens, attn_w, part,
                                               emb, chars, h_prev, w_ih, w_hh, zpart);
    // K2: LSTM gate epilogue ∪ attention chunk-combine  -> xcat2 = [context | h_new]
    gates_combine<<<dim3(256), 256, 0, stream>>>(zpart, b_ih, b_hh, c_prev, part, out, xcat2);
    // K3: concat projection split-K partials
    gemm_concat<<<dim3(64, 8), 256, 0, stream>>>(xcat2, concat_w, nhpart);
    // K4: nh reduce+tanh fused with vocab projection
    nh_out<<<dim3(32), 256, 0, stream>>>(nhpart, concat_b, out_w, out_b, out);
}